// Round 1
// baseline (2450.277 us; speedup 1.0000x reference)
//
#include <hip/hip_runtime.h>
#include <math.h>

// Problem constants (B, T, D_IN, D_OUT) = (64, 1024, 512, 512)
#define BATCH   64
#define TSTEPS  1024
#define DIN     512
#define DH      512
#define MDIM    (BATCH * TSTEPS)
#define MB      16

typedef _Float16 f16x8 __attribute__((ext_vector_type(8)));
typedef float    f32x4 __attribute__((ext_vector_type(4)));

__device__ inline unsigned short f2h_bits(float x) {
    _Float16 h = (_Float16)x;
    return __builtin_bit_cast(unsigned short, h);
}
// fast tanh: 1 - 2/(exp2(2x*log2e)+1); saturates correctly incl. inf
__device__ inline float ftanh(float x) {
    float e = __builtin_amdgcn_exp2f(x * 2.88539008177792681472f);
    return 1.0f - 2.0f * __builtin_amdgcn_rcpf(e + 1.0f);
}

// ---------------------------------------------------------------------------
// K1a: convert x (fp32) -> Xh (fp16)
// ---------------------------------------------------------------------------
__global__ __launch_bounds__(256) void convert_x(const float* __restrict__ x,
                                                 _Float16* __restrict__ xh,
                                                 int nvec) {
    int i = blockIdx.x * blockDim.x + threadIdx.x;
    int stride = gridDim.x * blockDim.x;
    for (; i < nvec; i += stride) {
        const float4* p = (const float4*)x + 2 * (size_t)i;
        float4 a = p[0], b = p[1];
        f16x8 o = { (_Float16)a.x, (_Float16)a.y, (_Float16)a.z, (_Float16)a.w,
                    (_Float16)b.x, (_Float16)b.y, (_Float16)b.z, (_Float16)b.w };
        ((f16x8*)xh)[i] = o;
    }
}

// ---------------------------------------------------------------------------
// K1b: Wt[n][k] = (fp16) W[k][n]   (also reused for Wr)
// ---------------------------------------------------------------------------
__global__ __launch_bounds__(256) void transpose_w(const float* __restrict__ W,
                                                   _Float16* __restrict__ Wt) {
    __shared__ float tile[64][65];
    const int t  = threadIdx.x;
    const int c  = t & 63;
    const int r0 = t >> 6;
    const int bn = blockIdx.x & 7;
    const int bk = blockIdx.x >> 3;
    const int k0 = bk * 64, n0 = bn * 64;
    #pragma unroll
    for (int i = 0; i < 16; ++i)
        tile[r0 + 4 * i][c] = W[(size_t)(k0 + r0 + 4 * i) * DH + n0 + c];
    __syncthreads();
    #pragma unroll
    for (int i = 0; i < 16; ++i)
        Wt[(size_t)(n0 + r0 + 4 * i) * DIN + k0 + c] = (_Float16)tile[c][r0 + 4 * i];
}

// ---------------------------------------------------------------------------
// K1c: XW = Xh @ Wt^T + bias via mfma_f32_16x16x32_f16 (validated earlier)
// ---------------------------------------------------------------------------
__global__ __launch_bounds__(256) void gemm_xw_mfma(const _Float16* __restrict__ Xh,
                                                    const _Float16* __restrict__ Wt,
                                                    const float* __restrict__ bias,
                                                    float* __restrict__ XW) {
    __shared__ __align__(16) _Float16 Ah[128][32];
    __shared__ __align__(16) _Float16 Bh[128][32];

    const int tid  = threadIdx.x;
    const int wv   = tid >> 6;
    const int lane = tid & 63;
    const int bn   = blockIdx.x & 3;
    const int bm   = blockIdx.x >> 2;
    const int m0   = bm * 128;
    const int n0   = bn * 128;

    const int mbase = (wv >> 1) * 64;
    const int nbase = (wv & 1) * 64;
    const int fr    = lane & 15;
    const int fq    = lane >> 4;

    f32x4 acc[4][4];
    #pragma unroll
    for (int i = 0; i < 4; ++i)
        #pragma unroll
        for (int j = 0; j < 4; ++j)
            acc[i][j] = (f32x4){0.f, 0.f, 0.f, 0.f};

    for (int kc = 0; kc < DIN / 32; ++kc) {
        const int k0 = kc * 32;
#if __has_builtin(__builtin_amdgcn_global_load_lds)
        #pragma unroll
        for (int q = 0; q < 2; ++q) {
            const int rb = wv * 2 + q;
            const int gr = (rb * 16) + (lane >> 2);
            const int gc = (lane & 3) * 8;
            const _Float16* ga = Xh + (size_t)(m0 + gr) * DIN + k0 + gc;
            const _Float16* gb = Wt + (size_t)(n0 + gr) * DIN + k0 + gc;
            __builtin_amdgcn_global_load_lds(
                (const __attribute__((address_space(1))) void*)ga,
                (__attribute__((address_space(3))) void*)&Ah[rb * 16][0], 16, 0, 0);
            __builtin_amdgcn_global_load_lds(
                (const __attribute__((address_space(1))) void*)gb,
                (__attribute__((address_space(3))) void*)&Bh[rb * 16][0], 16, 0, 0);
        }
#else
        #pragma unroll
        for (int q = 0; q < 2; ++q) {
            const int h0 = (q * 256 + tid) * 8;
            const int row = h0 >> 5, col = h0 & 31;
            *((uint4*)Ah + (q * 256 + tid)) =
                *(const uint4*)(Xh + (size_t)(m0 + row) * DIN + k0 + col);
            *((uint4*)Bh + (q * 256 + tid)) =
                *(const uint4*)(Wt + (size_t)(n0 + row) * DIN + k0 + col);
        }
#endif
        __syncthreads();

        f16x8 af[4], bf[4];
        #pragma unroll
        for (int mt = 0; mt < 4; ++mt)
            af[mt] = *(const f16x8*)&Ah[mbase + mt * 16 + fr][fq * 8];
        #pragma unroll
        for (int nt = 0; nt < 4; ++nt)
            bf[nt] = *(const f16x8*)&Bh[nbase + nt * 16 + fr][fq * 8];
        #pragma unroll
        for (int mt = 0; mt < 4; ++mt)
            #pragma unroll
            for (int nt = 0; nt < 4; ++nt)
                acc[mt][nt] = __builtin_amdgcn_mfma_f32_16x16x32_f16(
                    af[mt], bf[nt], acc[mt][nt], 0, 0, 0);
        __syncthreads();
    }

    #pragma unroll
    for (int nt = 0; nt < 4; ++nt) {
        const int col = n0 + nbase + nt * 16 + fr;
        const float bvl = bias[col];
        #pragma unroll
        for (int mt = 0; mt < 4; ++mt) {
            #pragma unroll
            for (int r = 0; r < 4; ++r) {
                const int row = m0 + mbase + mt * 16 + fq * 4 + r;
                XW[(size_t)row * DH + col] = acc[mt][nt][r] + bvl;
            }
        }
    }
}

// ---------------------------------------------------------------------------
// K1 fallback (fp32 VALU GEMM)
// ---------------------------------------------------------------------------
__global__ __launch_bounds__(256) void gemm_xw(const float* __restrict__ X,
                                               const float* __restrict__ W,
                                               const float* __restrict__ bias,
                                               float* __restrict__ XW) {
    __shared__ float As[16][68];
    __shared__ float Bs[16][68];
    const int tid = threadIdx.x;
    const int bx  = blockIdx.x & 7;
    const int by  = blockIdx.x >> 3;
    const int m0  = by * 64, n0 = bx * 64;
    const int ty = tid >> 4, tx = tid & 15;
    const int arow = tid >> 2, akq = (tid & 3) * 4;
    const int brow = tid >> 4, bcq = (tid & 15) * 4;
    float acc[4][4] = {{0.f}};
    for (int k0 = 0; k0 < DIN; k0 += 16) {
        float4 av = *(const float4*)&X[(size_t)(m0 + arow) * DIN + k0 + akq];
        float4 bv = *(const float4*)&W[(size_t)(k0 + brow) * DH + n0 + bcq];
        __syncthreads();
        As[akq + 0][arow] = av.x; As[akq + 1][arow] = av.y;
        As[akq + 2][arow] = av.z; As[akq + 3][arow] = av.w;
        *(float4*)&Bs[brow][bcq] = bv;
        __syncthreads();
        #pragma unroll
        for (int k = 0; k < 16; ++k) {
            float4 a = *(const float4*)&As[k][ty * 4];
            float4 b = *(const float4*)&Bs[k][tx * 4];
            float ar[4] = {a.x, a.y, a.z, a.w};
            float br[4] = {b.x, b.y, b.z, b.w};
            #pragma unroll
            for (int i = 0; i < 4; ++i)
                #pragma unroll
                for (int j = 0; j < 4; ++j)
                    acc[i][j] = fmaf(ar[i], br[j], acc[i][j]);
        }
    }
    float4 bv = *(const float4*)&bias[n0 + tx * 4];
    const float br[4] = {bv.x, bv.y, bv.z, bv.w};
    #pragma unroll
    for (int i = 0; i < 4; ++i) {
        float4 o;
        o.x = acc[i][0] + br[0]; o.y = acc[i][1] + br[1];
        o.z = acc[i][2] + br[2]; o.w = acc[i][3] + br[3];
        *(float4*)&XW[(size_t)(m0 + ty * 4 + i) * DH + n0 + tx * 4] = o;
    }
}

// ---------------------------------------------------------------------------
// K2: distributed MFMA scan. 8 wgs x 512 thr = 4 batch-groups x 2 halves.
// wg (g,p) owns batches [g*16,g*16+16) and output cols [p*256, p*256+256).
// Each wave owns 32 cols -> B (Wr) frags FULLY VGPR-resident (128 regs);
// zero per-step B LDS traffic (vs 128 KB/CU/step before).
// H[16][512] fp16 lives in LDS in FRAGMENT-LINEAR layout:
//   byte addr = chunk*1024 + (fq*16+fr)*16 + j*2  holds H[fr][chunk*32+fq*8+j]
// so every A-frag read is the canonical conflict-free ds_read_b128 pattern.
// Halves exchanged per step via agent-scope (sc1) stores/loads + a
// monotone "steps published" flag (release/acquire), double-buffered by
// step parity. Peer-load latency hides under the own-half MFMA phase.
// ---------------------------------------------------------------------------
__global__ __launch_bounds__(512, 2) void rnn_scan8(const float* __restrict__ XW,
                                                    const _Float16* __restrict__ Wrt,
                                                    float* __restrict__ Hout,
                                                    unsigned short* __restrict__ hbuf,
                                                    unsigned int* __restrict__ flags) {
    __shared__ __align__(16) _Float16 H[8192];   // 16 chunks x 1024 B, fragment-linear

    const int tid  = threadIdx.x;
    const int bid  = blockIdx.x;
    const int g    = bid >> 1;        // batch group 0..3
    const int p    = bid & 1;         // column half 0..1
    const int peer = bid ^ 1;
    const int wv   = tid >> 6;        // wave 0..7, owns cols [colbase, colbase+32)
    const int lane = tid & 63;
    const int fr   = lane & 15;
    const int fq   = lane >> 4;
    const int b0   = g * MB;
    const int colbase = p * 256 + wv * 32;

    // h0 = 0
    for (int i = tid; i < 4096; i += 512) ((unsigned int*)H)[i] = 0u;

    // B-frags, own-half chunks first (i<8 -> abs chunk 8p+i, else peer half).
    // Wrt[n][k] is the fp16 transpose of Wr, so frag loads are contiguous.
    f16x8 breg[2][16];
    #pragma unroll
    for (int s = 0; s < 2; ++s) {
        const int col = colbase + s * 16 + fr;
        #pragma unroll
        for (int i = 0; i < 16; ++i) {
            const int cabs = (i < 8) ? (8 * p + i) : (8 * (1 - p) + (i - 8));
            breg[s][i] = *(const f16x8*)&Wrt[(size_t)col * DIN + cabs * 32 + fq * 8];
        }
    }
    __syncthreads();

    unsigned short* myhb0   = hbuf + (size_t)bid  * 8192;  // 2 slots x 4096 halves
    unsigned short* peerhb0 = hbuf + (size_t)peer * 8192;
    unsigned int*   myflag   = flags + bid  * 64;
    unsigned int*   peerflag = flags + peer * 64;

    const int ownB  = p * 8192;       // byte offset of own 8 chunks in H
    const int peerB = 8192 - ownB;
    char* Hb = (char*)H;

    const float* xbase = XW + (size_t)(b0 + fq * 4) * TSTEPS * DH + colbase + fr;

    const int epi_slotbase = (fr >> 3) * 16 + fq * 4;      // + s*32 + r
    const int epi_off = (8 * p + wv) * 512 + (fr & 7);     // halves; + slot*8
    const int ghb_off = wv * 512 + (fr & 7);               // local-chunk-major

    #pragma unroll 1
    for (int t = 0; t < TSTEPS; ++t) {
        // ---- wait for peer H_t, issue its loads (latency hidden under own MFMA) ----
        unsigned long long pl0 = 0, pl1 = 0;
        if (t > 0) {
            if (tid == 0) {
                unsigned spins = 0;
                while (__hip_atomic_load(peerflag, __ATOMIC_ACQUIRE,
                                         __HIP_MEMORY_SCOPE_AGENT) < (unsigned)t) {
                    if (++spins > (1u << 17)) break;   // deadlock escape; never in practice
                }
            }
            __syncthreads();                           // barrier A
            unsigned long long* src =
                (unsigned long long*)(peerhb0 + (size_t)(t & 1) * 4096) + tid * 2;
            pl0 = __hip_atomic_load(src,     __ATOMIC_RELAXED, __HIP_MEMORY_SCOPE_AGENT);
            pl1 = __hip_atomic_load(src + 1, __ATOMIC_RELAXED, __HIP_MEMORY_SCOPE_AGENT);
        }

        f32x4 cc0 = {0.f, 0.f, 0.f, 0.f}, cc1 = {0.f, 0.f, 0.f, 0.f};

        // ---- own-half MFMA (abs chunks 8p..8p+7), conflict-free b128 reads ----
        #pragma unroll
        for (int i = 0; i < 8; ++i) {
            f16x8 af = *(const f16x8*)(Hb + ownB + i * 1024 + lane * 16);
            cc0 = __builtin_amdgcn_mfma_f32_16x16x32_f16(af, breg[0][i], cc0, 0, 0, 0);
            cc1 = __builtin_amdgcn_mfma_f32_16x16x32_f16(af, breg[1][i], cc1, 0, 0, 0);
        }

        // xw for this step in C-frag layout (issued early; consumed in epilogue)
        float xv[2][4];
        #pragma unroll
        for (int s = 0; s < 2; ++s)
            #pragma unroll
            for (int r = 0; r < 4; ++r)
                xv[s][r] = xbase[(size_t)r * TSTEPS * DH + (size_t)t * DH + s * 16];

        // publish peer half H_t into LDS (old peer data fully read last step)
        if (t > 0) {
            unsigned long long* dst = (unsigned long long*)(Hb + peerB + tid * 16);
            dst[0] = pl0; dst[1] = pl1;
        }
        __syncthreads();                               // barrier B

        // ---- peer-half MFMA ----
        #pragma unroll
        for (int i = 8; i < 16; ++i) {
            f16x8 af = *(const f16x8*)(Hb + peerB + (i - 8) * 1024 + lane * 16);
            cc0 = __builtin_amdgcn_mfma_f32_16x16x32_f16(af, breg[0][i], cc0, 0, 0, 0);
            cc1 = __builtin_amdgcn_mfma_f32_16x16x32_f16(af, breg[1][i], cc1, 0, 0, 0);
        }

        // ---- epilogue: h = tanh(acc + xw); write LDS (own region) + global slot ----
        unsigned short* myhb = myhb0 + (size_t)((t + 1) & 1) * 4096;
        #pragma unroll
        for (int s = 0; s < 2; ++s) {
            #pragma unroll
            for (int r = 0; r < 4; ++r) {
                const float a = (s == 0 ? cc0[r] : cc1[r]) + xv[s][r];
                const unsigned short hb16 = f2h_bits(ftanh(a));
                const int slot = epi_slotbase + s * 32 + r;
                ((unsigned short*)H)[epi_off + slot * 8] = hb16;
                __hip_atomic_store(myhb + ghb_off + slot * 8, hb16,
                                   __ATOMIC_RELAXED, __HIP_MEMORY_SCOPE_AGENT);
            }
        }
        __syncthreads();                               // barrier C (drains vmcnt)
        if (tid == 0)
            __hip_atomic_store(myflag, (unsigned)(t + 1),
                               __ATOMIC_RELEASE, __HIP_MEMORY_SCOPE_AGENT);
    }

    // final output: own half of H_T from LDS (coalesced float4 stores)
    {
        const int m    = tid >> 5;          // 0..15
        const int cg   = tid & 31;          // 8-col group within own half
        const int cabs = 8 * p + (cg >> 2);
        const int fqp  = cg & 3;
        f16x8 v = *(const f16x8*)(Hb + cabs * 1024 + (fqp * 16 + m) * 16);
        const int col = p * 256 + cg * 8;
        float4 o0 = { (float)v[0], (float)v[1], (float)v[2], (float)v[3] };
        float4 o1 = { (float)v[4], (float)v[5], (float)v[6], (float)v[7] };
        *(float4*)&Hout[(size_t)(b0 + m) * DH + col]     = o0;
        *(float4*)&Hout[(size_t)(b0 + m) * DH + col + 4] = o1;
    }
}

// ---------------------------------------------------------------------------
// launch
// ---------------------------------------------------------------------------
extern "C" void kernel_launch(void* const* d_in, const int* in_sizes, int n_in,
                              void* d_out, int out_size, void* d_ws, size_t ws_size,
                              hipStream_t stream) {
    const float* x  = (const float*)d_in[0];
    const float* W  = (const float*)d_in[1];
    const float* Wr = (const float*)d_in[2];
    const float* bv = (const float*)d_in[3];
    float* out = (float*)d_out;

    const size_t XW_BYTES   = (size_t)MDIM * DH * sizeof(float);       // 128 MiB
    const size_t HBUF_BYTES = (size_t)8 * 2 * 4096 * sizeof(unsigned short); // 128 KiB
    const size_t FLAG_BYTES = (size_t)8 * 64 * sizeof(unsigned int);   // 2 KiB
    const size_t WRT_BYTES  = (size_t)DH * DH * sizeof(_Float16);      // 512 KiB
    const size_t XH_BYTES   = (size_t)MDIM * DIN * sizeof(_Float16);   // 64 MiB
    const size_t WT_BYTES   = (size_t)DIN * DH * sizeof(_Float16);     // 512 KiB

    const size_t SCAN_MIN = XW_BYTES + HBUF_BYTES + FLAG_BYTES + WRT_BYTES;
    if (ws_size < SCAN_MIN) return;

    char* base = (char*)d_ws;
    float*          xw    = (float*)base;
    unsigned short* hbuf  = (unsigned short*)(base + XW_BYTES);
    unsigned int*   flags = (unsigned int*)(base + XW_BYTES + HBUF_BYTES);
    _Float16*       wrt   = (_Float16*)(base + XW_BYTES + HBUF_BYTES + FLAG_BYTES);

    hipMemsetAsync(flags, 0, FLAG_BYTES, stream);
    transpose_w<<<dim3(64), dim3(256), 0, stream>>>(Wr, wrt);

    if (ws_size >= SCAN_MIN + XH_BYTES + WT_BYTES) {
        _Float16* xh = (_Float16*)(base + SCAN_MIN);
        _Float16* wt = (_Float16*)(base + SCAN_MIN + XH_BYTES);
        convert_x<<<dim3(2048), dim3(256), 0, stream>>>(x, xh, MDIM * DIN / 8);
        transpose_w<<<dim3(64), dim3(256), 0, stream>>>(W, wt);
        gemm_xw_mfma<<<dim3((MDIM / 128) * (DH / 128)), dim3(256), 0, stream>>>(
            xh, wt, bv, xw);
    } else {
        gemm_xw<<<dim3((MDIM / 64) * (DH / 64)), dim3(256), 0, stream>>>(x, W, bv, xw);
    }

    rnn_scan8<<<dim3(8), dim3(512), 0, stream>>>(xw, wrt, out, hbuf, flags);
}